// Round 2
// baseline (305.598 us; speedup 1.0000x reference)
//
#include <hip/hip_runtime.h>

// DilatedConv1D: out[b,o,p] = bias[o] + sum_c x[b,c,p]*W[o,c,0] + x[b,c,p+2]*W[o,c,1]
// x: (8,128,32768) fp32, W: (128,128,2) fp32, bias: (128) fp32, out: (8,128,32769) fp32.
//
// Round-6 (de-risked round-5):
//  * out[:, :, 32768] == bias exactly (both taps hit the zero pad) -> main grid covers
//    p in [0,32768): 2048 tiles = 512 blocks x 4 tiles, perfectly balanced; blocks 0-7
//    write the bias column.
//  * Swapped MFMA operands: A = x (M=pos), B = W (N=o) -> each lane holds 4 consecutive
//    positions of one output row -> 16 B stores via __builtin_memcpy (out rows are only
//    4 B aligned since kP is odd; memcpy guarantees a correct lowering).
//  * float4 staging loads (16 dwordx4/thread), full-tile memory-level parallelism.
//  * Pipelined tiles, double-buffered LDS, loads for tile i+2 issued before a raw
//    lgkmcnt-only s_barrier so they stay in flight across it (T3/T4 pattern).
//  * XOR-swizzled LDS: conflict-free ds_write_b128, <=2-way (free) ds_read_b128.
//  * W fragments + bias registers loaded once per block.

namespace {

constexpr int kC   = 128;
constexpr int kT   = 32768;
constexpr int kP   = kT + 1;                    // 32769 output positions
constexpr int kOut = 128;
constexpr int kNP  = 128;                       // positions per tile
constexpr int kTilesPerB = kT / kNP;            // 256 (col 32768 handled separately)
constexpr int kUnitsPerBlock = 4;
constexpr int kNBlocks = 512;                   // 512*4 = 2048 = 8*256 units, exact
constexpr int kLStride = 136;                   // shorts per pos-row (272 B)
constexpr int kLBuf    = 130 * kLStride;        // 35360 B per buffer

typedef __attribute__((ext_vector_type(8))) short short8;
typedef __attribute__((ext_vector_type(4))) float f32x4;

// float -> bf16 bits, round-to-nearest-even (finite inputs)
__device__ __forceinline__ short f2bf(float f) {
    unsigned int u = __builtin_bit_cast(unsigned int, f);
    u += 0x7fffu + ((u >> 16) & 1u);
    return (short)(u >> 16);
}

// Swizzled LDS index (in shorts). XOR on c bits 3..5 keeps 8-short chunks contiguous
// and 16B-aligned. Write pattern (4 pos/lane): 8-lane groups cover all 32 banks ->
// conflict-free. Read pattern (16 consecutive pos per lane group): <=2-way (free).
__device__ __forceinline__ int lds_idx(int pos, int c) {
    return pos * kLStride + (c ^ (((pos >> 2) & 7) << 3));
}

// Raw barrier with LDS-only drain: in-flight global loads survive it.
__device__ __forceinline__ void lds_barrier() {
    asm volatile("s_waitcnt lgkmcnt(0)" ::: "memory");
    __builtin_amdgcn_s_barrier();
}

struct StageRegs {
    f32x4 m[16];   // main tile: 4 consecutive pos x 16 channels per thread
    float h[8];    // halo rows 128,129 (tid < 32 only)
};

// Issue global loads for one tile into registers.
// Thread -> 4 pos (tid&31) x 16 c (tid>>5). Main rows never need a guard
// (p0+127 <= 32767 for every tile); halo clamps (only tile 255 goes past kT).
__device__ __forceinline__ void stage_issue(const float* __restrict__ xb, int p0,
                                            int tid, StageRegs& r) {
    const int pgrp = tid & 31;
    const int cgrp = tid >> 5;
    const float* col = xb + p0 + pgrp * 4;
    #pragma unroll
    for (int j = 0; j < 16; ++j) {
        r.m[j] = *reinterpret_cast<const f32x4*>(col + ((size_t)(cgrp * 16 + j) << 15));
    }
    if (tid < 32) {
        const int gph = p0 + 128 + (tid & 1);
        const float* colh = xb + (gph < kT ? gph : 0);
        const int c0 = (tid >> 1) * 8;
        #pragma unroll
        for (int j = 0; j < 8; ++j) r.h[j] = colh[(size_t)(c0 + j) << 15];
    }
}

// Convert staged registers to bf16 and write the (swizzled) LDS buffer.
__device__ __forceinline__ void stage_commit(short* __restrict__ xs, int p0,
                                             int tid, const StageRegs& r) {
    const int pgrp = tid & 31;
    const int cgrp = tid >> 5;
    #pragma unroll
    for (int i = 0; i < 4; ++i) {
        const int pos = pgrp * 4 + i;
        #pragma unroll
        for (int h = 0; h < 2; ++h) {
            short8 v;
            #pragma unroll
            for (int j = 0; j < 8; ++j) v[j] = f2bf(r.m[h * 8 + j][i]);
            *reinterpret_cast<short8*>(xs + lds_idx(pos, cgrp * 16 + h * 8)) = v;
        }
    }
    if (tid < 32) {
        const int pos = 128 + (tid & 1);
        const bool okh = (p0 + pos) < kT;   // false only for tile 255 -> zero pad
        const int c0 = (tid >> 1) * 8;
        short8 v;
        #pragma unroll
        for (int j = 0; j < 8; ++j) v[j] = okh ? f2bf(r.h[j]) : (short)0;
        *reinterpret_cast<short8*>(xs + lds_idx(pos, c0)) = v;
    }
}

__global__ __launch_bounds__(256, 2) void dconv_mfma(
    const float* __restrict__ x, const float* __restrict__ W,
    const float* __restrict__ bias, float* __restrict__ out)
{
    __shared__ __align__(16) short xs[2][kLBuf];   // 70.7 KB -> 2 blocks/CU

    const int tid  = threadIdx.x;
    const int lane = tid & 63;
    const int wv   = tid >> 6;                  // wave -> output rows [32*wv, 32*wv+32)
    const int blk  = blockIdx.x;
    const int u0   = blk * kUnitsPerBlock;
    const int bb   = u0 >> 8;                   // all 4 tiles share one batch
    const int t0   = u0 & 255;

    // Trivial last column: out[b][o][32768] = bias[o].
    if (blk < 8 && tid < kOut) {
        out[(size_t)blk * kOut * kP + (size_t)tid * kP + kT] = bias[tid];
    }

    // ---------------- W fragments (B-operand: B[k][n], n = lane&15 = o,
    // k = (lane>>4)*8 + j = c), loaded once per block. ----------------
    const int rowbase = wv * 32;
    short8 wf[2][2][4];                         // [tap][o-chunk][kstep]
    #pragma unroll
    for (int cc = 0; cc < 2; ++cc) {
        const int o = rowbase + cc * 16 + (lane & 15);
        #pragma unroll
        for (int s = 0; s < 4; ++s) {
            const int cb = s * 32 + (lane >> 4) * 8;
            const f32x4* wp = reinterpret_cast<const f32x4*>(W + o * (kC * 2) + cb * 2);
            f32x4 wr[4];
            #pragma unroll
            for (int q = 0; q < 4; ++q) wr[q] = wp[q];
            short8 f0, f1;
            #pragma unroll
            for (int q = 0; q < 4; ++q) {
                f0[q * 2 + 0] = f2bf(wr[q][0]);  f1[q * 2 + 0] = f2bf(wr[q][1]);
                f0[q * 2 + 1] = f2bf(wr[q][2]);  f1[q * 2 + 1] = f2bf(wr[q][3]);
            }
            wf[0][cc][s] = f0;
            wf[1][cc][s] = f1;
        }
    }
    const float bv0 = bias[rowbase + (lane & 15)];
    const float bv1 = bias[rowbase + 16 + (lane & 15)];

    const float* xb = x + (size_t)bb * kC * kT;
    float* ob = out + (size_t)bb * kOut * kP;

    StageRegs r;
    // ---------------- prologue: stage tile t0, issue loads for t0+1 ----------------
    stage_issue(xb, t0 << 7, tid, r);
    stage_commit(xs[0], t0 << 7, tid, r);
    stage_issue(xb, (t0 + 1) << 7, tid, r);
    lds_barrier();

    // ---------------- pipelined main loop over 4 tiles ----------------
    #pragma unroll 1
    for (int i = 0; i < kUnitsPerBlock; ++i) {
        const short* cur = xs[i & 1];
        const int p0 = (t0 + i) << 7;

        // MFMA: D = x * W, D row = pos (lane>>4)*4+r, col = o (lane&15).
        f32x4 acc[2][8];                         // [o-chunk][pos-chunk]
        #pragma unroll
        for (int nc = 0; nc < 8; ++nc) {
            #pragma unroll
            for (int rr = 0; rr < 4; ++rr) { acc[0][nc][rr] = bv0; acc[1][nc][rr] = bv1; }
        }
        #pragma unroll
        for (int tap = 0; tap < 2; ++tap) {
            #pragma unroll
            for (int s = 0; s < 4; ++s) {
                const int cb = s * 32 + (lane >> 4) * 8;
                #pragma unroll
                for (int nc = 0; nc < 8; ++nc) {
                    const int pos = nc * 16 + (lane & 15) + 2 * tap;
                    const short8 xf = *reinterpret_cast<const short8*>(cur + lds_idx(pos, cb));
                    acc[0][nc] = __builtin_amdgcn_mfma_f32_16x16x32_bf16(xf, wf[tap][0][s], acc[0][nc], 0, 0, 0);
                    acc[1][nc] = __builtin_amdgcn_mfma_f32_16x16x32_bf16(xf, wf[tap][1][s], acc[1][nc], 0, 0, 0);
                }
            }
        }

        // Commit tile i+1 to the other buffer (vmcnt wait hidden under MFMA above).
        if (i + 1 < kUnitsPerBlock) {
            stage_commit(xs[(i + 1) & 1], (t0 + i + 1) << 7, tid, r);
        }

        // Stores: lane holds 4 consecutive positions of row o. Quartets of lanes
        // {l, l+16, l+32, l+48} merge into 64B runs across 16 rows. Rows are only
        // 4B-aligned (kP odd) -> memcpy for a guaranteed-correct 16B store lowering.
        {
            const int o0   = rowbase + (lane & 15);
            const int prow = (lane >> 4) * 4;
            #pragma unroll
            for (int nc = 0; nc < 8; ++nc) {
                const int p = p0 + nc * 16 + prow;
                #pragma unroll
                for (int cc = 0; cc < 2; ++cc) {
                    __builtin_memcpy(ob + (size_t)(o0 + cc * 16) * kP + p, &acc[cc][nc],
                                     sizeof(f32x4));
                }
            }
        }

        // Issue loads for tile i+2: in flight across the barrier and next MFMA phase.
        if (i + 2 < kUnitsPerBlock) {
            stage_issue(xb, (t0 + i + 2) << 7, tid, r);
        }

        if (i + 1 < kUnitsPerBlock) lds_barrier();
    }
}

}  // namespace

extern "C" void kernel_launch(void* const* d_in, const int* in_sizes, int n_in,
                              void* d_out, int out_size, void* d_ws, size_t ws_size,
                              hipStream_t stream) {
    const float* x    = (const float*)d_in[0];
    const float* W    = (const float*)d_in[1];
    const float* bias = (const float*)d_in[2];
    float* out        = (float*)d_out;

    dim3 grid(kNBlocks);   // 512 blocks = exactly 2 per CU, 4 tiles each
    dim3 block(256);
    hipLaunchKernelGGL(dconv_mfma, grid, block, 0, stream, x, W, bias, out);
}

// Round 3
// 290.204 us; speedup vs baseline: 1.0530x; 1.0530x over previous
//
#include <hip/hip_runtime.h>

// DilatedConv1D: out[b,o,p] = bias[o] + sum_c x[b,c,p]*W[o,c,0] + x[b,c,p+2]*W[o,c,1]
// x: (8,128,32768) fp32, W: (128,128,2) fp32, bias: (128) fp32, out: (8,128,32769) fp32.
//
// Round-7: async-DMA staging (global_load_lds), zero-VGPR loads.
//  Round-2 post-mortem: reg-staged "prefetch" was serialized by the register
//  allocator (VGPR_Count=128 << live estimate) -> ~1 KB in flight/wave -> 2 TB/s.
//  Now: HBM -(global_load_lds dwordx4, no VGPRs)-> fp32 LDS -(convert pass)->
//  bf16 LDS -> MFMA. 34 KB DMA per tile in flight across the whole MFMA+store
//  phase; one vmcnt(0) per tile.
//  * 512 blocks x 8 tiles of 64 pos; 2 blocks/CU (52.8 KB LDS).
//  * fp32 LDS rows are DMA-linear 256 B (bank-aligned); granule placement is
//    rotated via the SOURCE address (slot = (pw + c/4) & 15) so the convert
//    pass reads conflict-free. Same rotation applied on read. LDS stays linear.
//  * out[:, :, 32768] == bias exactly -> written by blocks 0-7.

namespace {

constexpr int kC   = 128;
constexpr int kT   = 32768;
constexpr int kP   = kT + 1;                  // 32769 output positions
constexpr int kOut = 128;
constexpr int kNP  = 64;                      // positions per tile
constexpr int kTilesPerBatch = kT / kNP;      // 512
constexpr int kTPB = 8;                       // tiles per block
constexpr int kNBlocks = 512;                 // 512*8 = 4096 = 8*512 units, exact
constexpr int kLStride = 136;                 // shorts per bf16 pos-row (272 B)
constexpr int kF32Main = 128 * 64;            // floats: 128 rows x 64 pos (256 B rows)
constexpr int kF32Halo = 128 * 4;             // floats: per-c 16 B halo granule

typedef __attribute__((ext_vector_type(8))) short short8;
typedef __attribute__((ext_vector_type(4))) short s16x4;
typedef __attribute__((ext_vector_type(4))) float f32x4;

// float -> bf16 bits, round-to-nearest-even (finite inputs)
__device__ __forceinline__ short f2bf(float f) {
    unsigned int u = __builtin_bit_cast(unsigned int, f);
    u += 0x7fffu + ((u >> 16) & 1u);
    return (short)(u >> 16);
}

// Async global->LDS DMA, 16 B/lane. LDS dest = l (wave-uniform) + lane*16.
__device__ __forceinline__ void dma16(const float* g, float* l) {
    __builtin_amdgcn_global_load_lds(
        (const __attribute__((address_space(1))) void*)g,
        (__attribute__((address_space(3))) void*)l,
        16, 0, 0);
}

__device__ __forceinline__ void wait_vm0_barrier() {
    asm volatile("s_waitcnt vmcnt(0)" ::: "memory");
    __builtin_amdgcn_s_barrier();
}
__device__ __forceinline__ void lds_barrier() {
    asm volatile("s_waitcnt lgkmcnt(0)" ::: "memory");
    __builtin_amdgcn_s_barrier();
}

// Issue the DMA for one 64-pos tile. 32 main instrs (4 channels x 16 slots each,
// 256 B contiguous per 16 lanes) + 2 halo instrs. Each wave issues 8 main;
// wave 0 issues the halo. No waits here.
__device__ __forceinline__ void stage_dma(const float* __restrict__ xb, int p0,
                                          int wv, int lane, float* __restrict__ xf,
                                          bool lastTile) {
    const int q = lane >> 4;       // channel-within-instr
    const int s = lane & 15;       // slot-within-row
    #pragma unroll
    for (int jj = 0; jj < 8; ++jj) {
        const int j  = wv * 8 + jj;            // row quad: c = 4j..4j+3
        const int c  = 4 * j + q;
        const int pw = (s - j) & 15;           // rotation: slot s holds granule pw
        dma16(xb + (size_t)c * kT + p0 + pw * 4, xf + j * 256);
    }
    if (wv == 0) {
        #pragma unroll
        for (int h = 0; h < 2; ++h) {
            const int c  = 64 * h + lane;
            const int gp = p0 + kNP;           // pos 64..67 (67 spills into next tile: harmless, L2-hot)
            dma16(xb + (size_t)c * kT + (lastTile ? p0 : gp),
                  xf + kF32Main + h * 256);
        }
    }
}

// fp32 LDS -> bf16 LDS. Thread: 4 channels (c0=4*(tid&31)) x 8 pos ((tid>>5)*8..).
// Reads use the same slot rotation as the DMA placement -> conflict-free.
__device__ __forceinline__ void convert_tile(const float* __restrict__ xf,
                                             short* __restrict__ xs,
                                             int tid, bool lastTile) {
    const int cg = tid & 31;
    const int c0 = cg * 4;
    const int ph = tid >> 5;
    #pragma unroll
    for (int u = 0; u < 2; ++u) {
        const int pw   = ph * 2 + u;
        const int slot = (pw + cg) & 15;
        f32x4 g[4];
        #pragma unroll
        for (int r = 0; r < 4; ++r) {
            g[r] = *reinterpret_cast<const f32x4*>(xf + (c0 + r) * 64 + slot * 4);
        }
        #pragma unroll
        for (int i = 0; i < 4; ++i) {
            const int pos = pw * 4 + i;
            s16x4 v;
            v[0] = f2bf(g[0][i]); v[1] = f2bf(g[1][i]);
            v[2] = f2bf(g[2][i]); v[3] = f2bf(g[3][i]);
            *reinterpret_cast<s16x4*>(xs + pos * kLStride + c0) = v;
        }
    }
    // halo rows 64,65 (zero for the final tile of the batch)
    if (tid < 128) {
        const int c = tid;
        const f32x4 hh = *reinterpret_cast<const f32x4*>(xf + kF32Main + c * 4);
        xs[64 * kLStride + c] = lastTile ? (short)0 : f2bf(hh[0]);
        xs[65 * kLStride + c] = lastTile ? (short)0 : f2bf(hh[1]);
    }
}

__global__ __launch_bounds__(256, 2) void dconv_mfma(
    const float* __restrict__ x, const float* __restrict__ W,
    const float* __restrict__ bias, float* __restrict__ out)
{
    __shared__ __align__(16) float xf[kF32Main + kF32Halo];   // 34.8 KB
    __shared__ __align__(16) short xs[66 * kLStride];         // 18.0 KB

    const int tid  = threadIdx.x;
    const int lane = tid & 63;
    const int wv   = tid >> 6;                 // wave -> output rows [32*wv, 32*wv+32)
    const int blk  = blockIdx.x;
    const int bb   = blk >> 6;                 // batch (64 blocks per batch)
    const int t0   = (blk & 63) * kTPB;        // first tile index within batch

    const float* xb = x + (size_t)bb * kC * kT;
    float* ob = out + (size_t)bb * kOut * kP;

    // Trivial last column: out[b][o][32768] = bias[o] (both taps hit the pad).
    if (blk < 8 && tid < kOut) {
        out[(size_t)blk * kOut * kP + (size_t)tid * kP + kT] = bias[tid];
    }

    // Prologue DMA for tile t0 (in flight under the W-fragment setup below).
    stage_dma(xb, t0 * kNP, wv, lane, xf, false);   // t0 < 511 always (t0 <= 504)

    // ---------------- W fragments (B-operand: B[k][n], n = lane&15 = o,
    // k = (lane>>4)*8 + j = c), loaded once per block. ----------------
    const int rowbase = wv * 32;
    short8 wf[2][2][4];                         // [tap][o-chunk][kstep]
    #pragma unroll
    for (int cc = 0; cc < 2; ++cc) {
        const int o = rowbase + cc * 16 + (lane & 15);
        #pragma unroll
        for (int s = 0; s < 4; ++s) {
            const int cb = s * 32 + (lane >> 4) * 8;
            const f32x4* wp = reinterpret_cast<const f32x4*>(W + o * (kC * 2) + cb * 2);
            f32x4 wr[4];
            #pragma unroll
            for (int q = 0; q < 4; ++q) wr[q] = wp[q];
            short8 f0, f1;
            #pragma unroll
            for (int q = 0; q < 4; ++q) {
                f0[q * 2 + 0] = f2bf(wr[q][0]);  f1[q * 2 + 0] = f2bf(wr[q][1]);
                f0[q * 2 + 1] = f2bf(wr[q][2]);  f1[q * 2 + 1] = f2bf(wr[q][3]);
            }
            wf[0][cc][s] = f0;
            wf[1][cc][s] = f1;
        }
    }
    const float bv0 = bias[rowbase + (lane & 15)];
    const float bv1 = bias[rowbase + 16 + (lane & 15)];

    wait_vm0_barrier();    // tile t0 fp32 data landed

    // ---------------- pipelined main loop over 8 tiles ----------------
    #pragma unroll 1
    for (int i = 0; i < kTPB; ++i) {
        const int p0 = (t0 + i) * kNP;
        const bool lastTile = (t0 + i) == (kTilesPerBatch - 1);

        convert_tile(xf, xs, tid, lastTile);
        lds_barrier();                          // bf16 ready; fp32 buffer free

        // Issue next tile's DMA: in flight across MFMA + stores below.
        if (i + 1 < kTPB) {
            stage_dma(xb, (t0 + i + 1) * kNP, wv, lane, xf,
                      (t0 + i + 1) == (kTilesPerBatch - 1));
        }

        // MFMA: D = x * W; D row = pos (lane>>4)*4+rr, col = o (lane&15).
        f32x4 acc[2][4];                        // [o-chunk][pos-chunk]
        #pragma unroll
        for (int nc = 0; nc < 4; ++nc) {
            #pragma unroll
            for (int rr = 0; rr < 4; ++rr) { acc[0][nc][rr] = bv0; acc[1][nc][rr] = bv1; }
        }
        #pragma unroll
        for (int tap = 0; tap < 2; ++tap) {
            #pragma unroll
            for (int s = 0; s < 4; ++s) {
                const int cb = s * 32 + (lane >> 4) * 8;
                #pragma unroll
                for (int nc = 0; nc < 4; ++nc) {
                    const int pos = nc * 16 + (lane & 15) + 2 * tap;
                    const short8 xfrag = *reinterpret_cast<const short8*>(xs + pos * kLStride + cb);
                    acc[0][nc] = __builtin_amdgcn_mfma_f32_16x16x32_bf16(xfrag, wf[tap][0][s], acc[0][nc], 0, 0, 0);
                    acc[1][nc] = __builtin_amdgcn_mfma_f32_16x16x32_bf16(xfrag, wf[tap][1][s], acc[1][nc], 0, 0, 0);
                }
            }
        }

        // Stores: lane holds 4 consecutive positions of row o; lanes {l,l+16,l+32,l+48}
        // form 64 B runs. Rows only 4 B aligned (kP odd) -> memcpy lowering.
        {
            const int o0   = rowbase + (lane & 15);
            const int prow = (lane >> 4) * 4;
            #pragma unroll
            for (int nc = 0; nc < 4; ++nc) {
                const int p = p0 + nc * 16 + prow;
                #pragma unroll
                for (int cc = 0; cc < 2; ++cc) {
                    __builtin_memcpy(ob + (size_t)(o0 + cc * 16) * kP + p, &acc[cc][nc],
                                     sizeof(f32x4));
                }
            }
        }

        if (i + 1 < kTPB) wait_vm0_barrier();   // next tile's fp32 landed; xs reusable
    }
}

}  // namespace

extern "C" void kernel_launch(void* const* d_in, const int* in_sizes, int n_in,
                              void* d_out, int out_size, void* d_ws, size_t ws_size,
                              hipStream_t stream) {
    const float* x    = (const float*)d_in[0];
    const float* W    = (const float*)d_in[1];
    const float* bias = (const float*)d_in[2];
    float* out        = (float*)d_out;

    dim3 grid(kNBlocks);   // 512 blocks = 2 per CU, 8 tiles each
    dim3 block(256);
    hipLaunchKernelGGL(dconv_mfma, grid, block, 0, stream, x, W, bias, out);
}